// Round 8
// baseline (760.057 us; speedup 1.0000x reference)
//
#include <hip/hip_runtime.h>
#include <hip/hip_cooperative_groups.h>
#include <hip/hip_bf16.h>
#include <math.h>

namespace cg = cooperative_groups;

#define F_IN 128
#define F_HID 256
#define F_OUT 10

typedef __attribute__((ext_vector_type(8))) short s16x8;
typedef __attribute__((ext_vector_type(4))) float f32x4;

static __device__ __forceinline__ float b2f(unsigned short u) {
    union { float f; unsigned int u; } c;
    c.u = ((unsigned int)u) << 16;
    return c.f;
}
static __device__ __forceinline__ unsigned short f2b(float f) {
    return __bfloat16_as_ushort(__float2bfloat16(f));
}

// ---------------- cooperative build: zero+casts -> count -> scan -> fill ----------------

__global__ void __launch_bounds__(256) build_kernel(
    const int* __restrict__ src, const int* __restrict__ dst, int e, int n,
    const float* __restrict__ x, unsigned short* __restrict__ xb,
    const float* __restrict__ W1, unsigned short* __restrict__ W1t,
    const float* __restrict__ W2, unsigned short* __restrict__ W2t,
    int* __restrict__ cnt, int* __restrict__ cursor, int* __restrict__ rowstart,
    int* __restrict__ partial, float* __restrict__ dinv, int2* __restrict__ pack)
{
    cg::grid_group grid = cg::this_grid();
    const int tid = threadIdx.x;
    const int gtid = blockIdx.x * 256 + tid;
    const int gs = gridDim.x * 256;

    // A0: zero counters + bf16 casts
    for (int i = gtid; i < n; i += gs) { cnt[i] = 0; cursor[i] = 0; }
    const int xq = n * (F_IN / 4);
    for (int i = gtid; i < xq; i += gs) {
        float4 v = *(const float4*)&x[(size_t)i * 4];
        ushort4 o;
        o.x = f2b(v.x); o.y = f2b(v.y); o.z = f2b(v.z); o.w = f2b(v.w);
        *(ushort4*)&xb[(size_t)i * 4] = o;
    }
    for (int i = gtid; i < F_IN * F_HID; i += gs) {
        int k = i / F_HID, nn = i - k * F_HID;
        W1t[nn * F_IN + k] = f2b(W1[i]);
    }
    for (int i = gtid; i < F_HID * F_HID; i += gs) {
        int k = i / F_HID, nn = i - k * F_HID;
        W2t[nn * F_HID + k] = f2b(W2[i]);
    }
    grid.sync();

    // A1: degree count
    for (int i = gtid; i < e; i += gs) atomicAdd(&cnt[dst[i]], 1);
    grid.sync();

    // B1: per-256-chunk exclusive scan
    __shared__ int s[256];
    const int nb = (n + 255) >> 8;
    if ((int)blockIdx.x < nb) {
        int i = blockIdx.x * 256 + tid;
        int v = (i < n) ? cnt[i] : 0;
        s[tid] = v;
        __syncthreads();
        for (int o = 1; o < 256; o <<= 1) {
            int t = (tid >= o) ? s[tid - o] : 0;
            __syncthreads();
            s[tid] += t;
            __syncthreads();
        }
        if (i < n) rowstart[i] = s[tid] - v;
        if (tid == 255) partial[blockIdx.x] = s[255];
    }
    grid.sync();

    // B2: scan chunk totals (nb <= 256)
    if (blockIdx.x == 0) {
        int v = (tid < nb) ? partial[tid] : 0;
        s[tid] = v;
        __syncthreads();
        for (int o = 1; o < 256; o <<= 1) {
            int t = (tid >= o) ? s[tid - o] : 0;
            __syncthreads();
            s[tid] += t;
            __syncthreads();
        }
        if (tid < nb) partial[tid] = s[tid] - v;
    }
    grid.sync();

    // B3: add chunk offsets + dinv
    for (int i = gtid; i < n; i += gs) {
        rowstart[i] += partial[i >> 8];
        dinv[i] = rsqrtf((float)(cnt[i] + 1));  // +1 self loop
    }
    if (gtid == 0) rowstart[n] = e;
    grid.sync();

    // C: fill packed CSR {src, norm}
    for (int i = gtid; i < e; i += gs) {
        int ss = src[i], d = dst[i];
        int pos = rowstart[d] + atomicAdd(&cursor[d], 1);
        pack[pos] = make_int2(ss, __float_as_int(dinv[ss] * dinv[d]));
    }
}

// ---------------- aggregation: wave per node, 16B/lane, edge-group parallel ----------------

template <int F>
__global__ __launch_bounds__(256) void agg_kernel(const unsigned short* __restrict__ feat,
                                                  const int* __restrict__ rowstart,
                                                  const int2* __restrict__ pack,
                                                  const float* __restrict__ dinv,
                                                  unsigned short* __restrict__ out, int n) {
    constexpr int LPF = F / 8;       // lanes per feature row
    constexpr int EG = 64 / LPF;     // edge groups per wave
    int wid = threadIdx.x >> 6;
    int lane = threadIdx.x & 63;
    int v = blockIdx.x * 4 + wid;
    if (v >= n) return;
    int eg = lane / LPF;
    int fl = lane % LPF;
    const unsigned short* fp = feat + fl * 8;

    float acc[8];
    {
        float d = dinv[v];
        float sw = (eg == 0) ? d * d : 0.f;
        s16x8 t = *(const s16x8*)&fp[(size_t)v * F];
#pragma unroll
        for (int j = 0; j < 8; ++j) acc[j] = sw * b2f((unsigned short)t[j]);
    }

    int e0 = rowstart[v], e1 = rowstart[v + 1];
    constexpr int STEP = EG * 4;
    int e = e0;
    for (; e + STEP <= e1; e += STEP) {
        int2 p[4];
#pragma unroll
        for (int u = 0; u < 4; ++u) p[u] = pack[e + eg + u * EG];
        s16x8 t[4];
#pragma unroll
        for (int u = 0; u < 4; ++u) t[u] = *(const s16x8*)&fp[(size_t)p[u].x * F];
#pragma unroll
        for (int u = 0; u < 4; ++u) {
            float w = __int_as_float(p[u].y);
#pragma unroll
            for (int j = 0; j < 8; ++j) acc[j] += w * b2f((unsigned short)t[u][j]);
        }
    }
    for (int ee = e + eg; ee < e1; ee += EG) {
        int2 p = pack[ee];
        float w = __int_as_float(p.y);
        s16x8 t = *(const s16x8*)&fp[(size_t)p.x * F];
#pragma unroll
        for (int j = 0; j < 8; ++j) acc[j] += w * b2f((unsigned short)t[j]);
    }

    if (EG == 4) {
#pragma unroll
        for (int j = 0; j < 8; ++j) acc[j] += __shfl_xor(acc[j], 16);
    }
#pragma unroll
    for (int j = 0; j < 8; ++j) acc[j] += __shfl_xor(acc[j], 32);

    if (eg == 0) {
        s16x8 o;
#pragma unroll
        for (int j = 0; j < 8; ++j) o[j] = (short)f2b(acc[j]);
        *(s16x8*)&out[(size_t)v * F + fl * 8] = o;
    }
}

// ---------------- MFMA bf16 GEMM, full-N tile 64x256, 4 waves (16 rows x 256 cols each) ----
// FUSE3=false: write relu(A@W+b) as bf16 to Cb.
// FUSE3=true:  compute hw3 = relu(A@W+b) @ W3 in-register (full K in block), direct store.
// Fragments: lane=g*16+r16; A k-slots = As[row][g*8..g*8+8]; B same -> shared k-perm (valid).

template <int K, bool FUSE3>
__global__ __launch_bounds__(256) void gemm_kernel(const unsigned short* __restrict__ A,
                                                   const unsigned short* __restrict__ Bt,
                                                   const float* __restrict__ bias,
                                                   unsigned short* __restrict__ Cb,
                                                   const float* __restrict__ W3,
                                                   float* __restrict__ hw3, int M) {
    constexpr int N = F_HID;
    __shared__ unsigned short As[64][40];   // 80B stride: 16B-aligned, 2-way banks max
    __shared__ unsigned short Bs[N][40];
    const int tid = threadIdx.x;
    const int w = tid >> 6, lane = tid & 63;
    const int g = lane >> 4, r16 = lane & 15;
    const int bm = blockIdx.x;

    const int sArow = tid >> 2;
    const int sAkq = (tid & 3) * 8;
    const int garow = bm * 64 + sArow;

    f32x4 acc[16] = {};

    for (int k0 = 0; k0 < K; k0 += 32) {
        uint4 av = make_uint4(0, 0, 0, 0);
        if (garow < M) av = *(const uint4*)&A[(size_t)garow * K + k0 + sAkq];
        uint4 bv0 = *(const uint4*)&Bt[(size_t)tid * K + k0 + 0];
        uint4 bv1 = *(const uint4*)&Bt[(size_t)tid * K + k0 + 8];
        uint4 bv2 = *(const uint4*)&Bt[(size_t)tid * K + k0 + 16];
        uint4 bv3 = *(const uint4*)&Bt[(size_t)tid * K + k0 + 24];
        __syncthreads();   // protect previous iteration's LDS reads
        *(uint4*)&As[sArow][sAkq] = av;
        *(uint4*)&Bs[tid][0] = bv0;
        *(uint4*)&Bs[tid][8] = bv1;
        *(uint4*)&Bs[tid][16] = bv2;
        *(uint4*)&Bs[tid][24] = bv3;
        __syncthreads();

        s16x8 af = *(const s16x8*)&As[w * 16 + r16][g * 8];
#pragma unroll
        for (int cg = 0; cg < 16; ++cg) {
            s16x8 bf = *(const s16x8*)&Bs[cg * 16 + r16][g * 8];
            acc[cg] = __builtin_amdgcn_mfma_f32_16x16x32_bf16(af, bf, acc[cg], 0, 0, 0);
        }
    }

    // C/D layout: col = cg*16 + (lane&15); row (within wave) = (lane>>4)*4 + reg
    if constexpr (!FUSE3) {
#pragma unroll
        for (int cg = 0; cg < 16; ++cg) {
            int col = cg * 16 + r16;
            float bs = bias[col];
#pragma unroll
            for (int r = 0; r < 4; ++r) {
                int row = bm * 64 + w * 16 + g * 4 + r;
                if (row < M) {
                    float v = fmaxf(acc[cg][r] + bs, 0.f);
                    Cb[(size_t)row * N + col] = f2b(v);
                }
            }
        }
    } else {
        // stage W3 [256][10] fp32 into LDS (reuse Bs region)
        float* W3s = (float*)&Bs[0][0];
        __syncthreads();
        for (int i = tid; i < N * F_OUT; i += 256) W3s[i] = W3[i];
        __syncthreads();

        float bcol[16];
#pragma unroll
        for (int cg = 0; cg < 16; ++cg) bcol[cg] = bias[cg * 16 + r16];

#pragma unroll
        for (int r = 0; r < 4; ++r) {
            float pj[F_OUT] = {};
#pragma unroll
            for (int cg = 0; cg < 16; ++cg) {
                float v = fmaxf(acc[cg][r] + bcol[cg], 0.f);
                const float* w3r = &W3s[(cg * 16 + r16) * F_OUT];
#pragma unroll
                for (int j = 0; j < F_OUT; ++j) pj[j] += v * w3r[j];
            }
#pragma unroll
            for (int j = 0; j < F_OUT; ++j) {
                pj[j] += __shfl_xor(pj[j], 1);
                pj[j] += __shfl_xor(pj[j], 2);
                pj[j] += __shfl_xor(pj[j], 4);
                pj[j] += __shfl_xor(pj[j], 8);
            }
            if (r16 == 0) {
                int row = bm * 64 + w * 16 + g * 4 + r;
                if (row < M) {
#pragma unroll
                    for (int j = 0; j < F_OUT; ++j) hw3[(size_t)row * F_OUT + j] = pj[j];
                }
            }
        }
    }
}

// ---------------- final: 10-dim aggregation + bias + log_softmax ----------------

__global__ void final_kernel(const float* __restrict__ hw3, const int* __restrict__ rowstart,
                             const int2* __restrict__ pack, const float* __restrict__ dinv,
                             const float* __restrict__ b3, float* __restrict__ out, int n) {
    int v = blockIdx.x * blockDim.x + threadIdx.x;
    if (v >= n) return;
    float acc[F_OUT];
    float d = dinv[v];
    float sw = d * d;
#pragma unroll
    for (int j = 0; j < F_OUT; ++j) acc[j] = sw * hw3[(size_t)v * F_OUT + j];
    int e0 = rowstart[v], e1 = rowstart[v + 1];
    for (int e = e0; e < e1; ++e) {
        int2 p = pack[e];
        float w = __int_as_float(p.y);
#pragma unroll
        for (int j = 0; j < F_OUT; ++j) acc[j] += w * hw3[(size_t)p.x * F_OUT + j];
    }
#pragma unroll
    for (int j = 0; j < F_OUT; ++j) acc[j] += b3[j];
    float m = acc[0];
#pragma unroll
    for (int j = 1; j < F_OUT; ++j) m = fmaxf(m, acc[j]);
    float sum = 0.f;
#pragma unroll
    for (int j = 0; j < F_OUT; ++j) sum += expf(acc[j] - m);
    float lse = m + logf(sum);
#pragma unroll
    for (int j = 0; j < F_OUT; ++j) out[(size_t)v * F_OUT + j] = acc[j] - lse;
}

// ---------------- launch ----------------

extern "C" void kernel_launch(void* const* d_in, const int* in_sizes, int n_in,
                              void* d_out, int out_size, void* d_ws, size_t ws_size,
                              hipStream_t stream) {
    const float* x  = (const float*)d_in[0];
    const int*   ei = (const int*)d_in[1];
    const float* W1 = (const float*)d_in[2];
    const float* b1 = (const float*)d_in[3];
    const float* W2 = (const float*)d_in[4];
    const float* b2 = (const float*)d_in[5];
    const float* W3 = (const float*)d_in[6];
    const float* b3 = (const float*)d_in[7];
    float* out = (float*)d_out;

    int n = in_sizes[0] / F_IN;
    int e = in_sizes[1] / 2;
    const int* srcp = ei;
    const int* dstp = ei + e;

    size_t off = 0;
    auto alloc = [&](size_t bytes) -> char* {
        char* p = (char*)d_ws + off;
        off += (bytes + 255) & ~(size_t)255;
        return p;
    };
    int*   cnt      = (int*)alloc((size_t)n * 4);
    int*   cursor   = (int*)alloc((size_t)n * 4);
    int*   rowstart = (int*)alloc((size_t)(n + 1) * 4);
    int*   partial  = (int*)alloc(1024 * 4);
    int2*  pack     = (int2*)alloc((size_t)e * 8);
    float* dinv     = (float*)alloc((size_t)n * 4);
    unsigned short* xb   = (unsigned short*)alloc((size_t)n * F_IN * 2);   // x bf16
    unsigned short* aggb = (unsigned short*)alloc((size_t)n * F_HID * 2);  // agg out bf16
    unsigned short* h1b  = (unsigned short*)alloc((size_t)n * F_HID * 2);  // h1 bf16
    unsigned short* W1t  = (unsigned short*)alloc((size_t)F_IN * F_HID * 2);
    unsigned short* W2t  = (unsigned short*)alloc((size_t)F_HID * F_HID * 2);
    float* hw3 = (float*)alloc((size_t)n * F_OUT * 4);

    // 1) cooperative build (zero + casts + count + scan + fill)
    void* args[] = { (void*)&srcp, (void*)&dstp, (void*)&e, (void*)&n,
                     (void*)&x, (void*)&xb, (void*)&W1, (void*)&W1t,
                     (void*)&W2, (void*)&W2t,
                     (void*)&cnt, (void*)&cursor, (void*)&rowstart,
                     (void*)&partial, (void*)&dinv, (void*)&pack };
    hipLaunchCooperativeKernel((void*)build_kernel, dim3(1024), dim3(256), args, 0, stream);

    int nwave = (n + 3) / 4;
    int gblocks = (n + 63) / 64;

    // 2) layer-1 aggregation (128-dim gather)
    agg_kernel<F_IN><<<nwave, 256, 0, stream>>>(xb, rowstart, pack, dinv, aggb, n);
    // 3) h1 = relu(agg @ W1 + b1), bf16
    gemm_kernel<F_IN, false><<<gblocks, 256, 0, stream>>>(aggb, W1t, b1, h1b, nullptr, nullptr, n);
    // 4) layer-2 aggregation (256-dim gather)
    agg_kernel<F_HID><<<nwave, 256, 0, stream>>>(h1b, rowstart, pack, dinv, aggb, n);
    // 5) hw3 = relu(agg @ W2 + b2) @ W3  (gemm3 fused, fp32 h2 in-register)
    gemm_kernel<F_HID, true><<<gblocks, 256, 0, stream>>>(aggb, W2t, b2, nullptr, W3, hw3, n);
    // 6) final: 10-dim aggregation + bias + log_softmax
    final_kernel<<<(n + 255) / 256, 256, 0, stream>>>(hw3, rowstart, pack, dinv, b3, out, n);
}

// Round 9
// 263.788 us; speedup vs baseline: 2.8813x; 2.8813x over previous
//
#include <hip/hip_runtime.h>
#include <hip/hip_bf16.h>
#include <math.h>

#define F_IN 128
#define F_HID 256
#define F_OUT 10

typedef __attribute__((ext_vector_type(8))) short s16x8;
typedef __attribute__((ext_vector_type(4))) float f32x4;

static __device__ __forceinline__ float b2f(unsigned short u) {
    union { float f; unsigned int u; } c;
    c.u = ((unsigned int)u) << 16;
    return c.f;
}
static __device__ __forceinline__ unsigned short f2b(float f) {
    return __bfloat16_as_ushort(__float2bfloat16(f));
}

// ---------------- fused prep: degree count + bf16 casts ----------------
// blockIdx.y: 0=count, 1=cast x, 2=castT W1, 3=castT W2

__global__ void prep_kernel(const int* __restrict__ dst, int* __restrict__ cnt, int e,
                            const float* __restrict__ x, unsigned short* __restrict__ xb,
                            int xq,
                            const float* __restrict__ W1, unsigned short* __restrict__ W1t,
                            const float* __restrict__ W2, unsigned short* __restrict__ W2t) {
    int i = blockIdx.x * blockDim.x + threadIdx.x;
    int job = blockIdx.y;
    if (job == 0) {
        if (i < e) atomicAdd(&cnt[dst[i]], 1);
    } else if (job == 1) {
        if (i < xq) {
            float4 v = *(const float4*)&x[(size_t)i * 4];
            ushort4 o;
            o.x = f2b(v.x); o.y = f2b(v.y); o.z = f2b(v.z); o.w = f2b(v.w);
            *(ushort4*)&xb[(size_t)i * 4] = o;
        }
    } else if (job == 2) {
        if (i < F_IN * F_HID) {
            int k = i / F_HID, nn = i - k * F_HID;
            W1t[nn * F_IN + k] = f2b(W1[i]);
        }
    } else {
        if (i < F_HID * F_HID) {
            int k = i / F_HID, nn = i - k * F_HID;
            W2t[nn * F_HID + k] = f2b(W2[i]);
        }
    }
}

// ---------------- scan (rowstart) + dinv ----------------

__global__ void scan1_kernel(const int* __restrict__ cnt, int* __restrict__ rowstart,
                             int* __restrict__ partial, float* __restrict__ dinv, int n) {
    __shared__ int s[256];
    int tid = threadIdx.x;
    int i = blockIdx.x * 256 + tid;
    int v = (i < n) ? cnt[i] : 0;
    s[tid] = v;
    __syncthreads();
    for (int off = 1; off < 256; off <<= 1) {
        int t = (tid >= off) ? s[tid - off] : 0;
        __syncthreads();
        s[tid] += t;
        __syncthreads();
    }
    if (i < n) {
        rowstart[i] = s[tid] - v;                 // exclusive
        dinv[i] = rsqrtf((float)(v + 1));         // +1 self loop
    }
    if (tid == 255) partial[blockIdx.x] = s[255]; // block total
}

__global__ void scan2_kernel(int* __restrict__ partial, int nb) {
    __shared__ int s[256];
    int tid = threadIdx.x;
    int v = (tid < nb) ? partial[tid] : 0;
    s[tid] = v;
    __syncthreads();
    for (int off = 1; off < 256; off <<= 1) {
        int t = (tid >= off) ? s[tid - off] : 0;
        __syncthreads();
        s[tid] += t;
        __syncthreads();
    }
    if (tid < nb) partial[tid] = s[tid] - v;      // exclusive block offsets
}

__global__ void scan3_kernel(int* __restrict__ rowstart, const int* __restrict__ partial,
                             int n, int e) {
    int i = blockIdx.x * blockDim.x + threadIdx.x;
    if (i < n) rowstart[i] += partial[blockIdx.x];
    if (i == 0) rowstart[n] = e;
}

__global__ void fill_kernel(const int* __restrict__ src, const int* __restrict__ dst,
                            const int* __restrict__ rowstart, int* __restrict__ cursor,
                            const float* __restrict__ dinv, int2* __restrict__ pack, int e) {
    int i = blockIdx.x * blockDim.x + threadIdx.x;
    if (i >= e) return;
    int s = src[i], d = dst[i];
    int pos = rowstart[d] + atomicAdd(&cursor[d], 1);
    float w = dinv[s] * dinv[d];
    pack[pos] = make_int2(s, __float_as_int(w));
}

// ---------------- aggregation: wave per node, 16B/lane, edge-group parallel ----------------

template <int F>
__global__ __launch_bounds__(256) void agg_kernel(const unsigned short* __restrict__ feat,
                                                  const int* __restrict__ rowstart,
                                                  const int2* __restrict__ pack,
                                                  const float* __restrict__ dinv,
                                                  unsigned short* __restrict__ out, int n) {
    constexpr int LPF = F / 8;       // lanes per feature row
    constexpr int EG = 64 / LPF;     // edge groups per wave
    int wid = threadIdx.x >> 6;
    int lane = threadIdx.x & 63;
    int v = blockIdx.x * 4 + wid;
    if (v >= n) return;
    int eg = lane / LPF;
    int fl = lane % LPF;
    const unsigned short* fp = feat + fl * 8;

    float acc[8];
    {
        float d = dinv[v];
        float sw = (eg == 0) ? d * d : 0.f;
        s16x8 t = *(const s16x8*)&fp[(size_t)v * F];
#pragma unroll
        for (int j = 0; j < 8; ++j) acc[j] = sw * b2f((unsigned short)t[j]);
    }

    int e0 = rowstart[v], e1 = rowstart[v + 1];
    constexpr int STEP = EG * 4;
    int e = e0;
    for (; e + STEP <= e1; e += STEP) {
        int2 p[4];
#pragma unroll
        for (int u = 0; u < 4; ++u) p[u] = pack[e + eg + u * EG];
        s16x8 t[4];
#pragma unroll
        for (int u = 0; u < 4; ++u) t[u] = *(const s16x8*)&fp[(size_t)p[u].x * F];
#pragma unroll
        for (int u = 0; u < 4; ++u) {
            float w = __int_as_float(p[u].y);
#pragma unroll
            for (int j = 0; j < 8; ++j) acc[j] += w * b2f((unsigned short)t[u][j]);
        }
    }
    for (int ee = e + eg; ee < e1; ee += EG) {
        int2 p = pack[ee];
        float w = __int_as_float(p.y);
        s16x8 t = *(const s16x8*)&fp[(size_t)p.x * F];
#pragma unroll
        for (int j = 0; j < 8; ++j) acc[j] += w * b2f((unsigned short)t[j]);
    }

    if (EG == 4) {
#pragma unroll
        for (int j = 0; j < 8; ++j) acc[j] += __shfl_xor(acc[j], 16);
    }
#pragma unroll
    for (int j = 0; j < 8; ++j) acc[j] += __shfl_xor(acc[j], 32);

    if (eg == 0) {
        s16x8 o;
#pragma unroll
        for (int j = 0; j < 8; ++j) o[j] = (short)f2b(acc[j]);
        *(s16x8*)&out[(size_t)v * F + fl * 8] = o;
    }
}

// ---------------- MFMA bf16 GEMM, full-N tile 64x256, 4 waves (16 rows x 256 cols each) ----
// FUSE3=false: write relu(A@W+b) as bf16 to Cb.
// FUSE3=true:  compute hw3 = relu(A@W+b) @ W3 in-register (full K in block), direct store.
// Fragments: lane=g*16+r16; A k-slots = As[row][g*8..g*8+8]; B same -> shared k-perm (valid).

template <int K, bool FUSE3>
__global__ __launch_bounds__(256) void gemm_kernel(const unsigned short* __restrict__ A,
                                                   const unsigned short* __restrict__ Bt,
                                                   const float* __restrict__ bias,
                                                   unsigned short* __restrict__ Cb,
                                                   const float* __restrict__ W3,
                                                   float* __restrict__ hw3, int M) {
    constexpr int N = F_HID;
    __shared__ unsigned short As[64][40];   // 80B stride: 16B-aligned, 2-way banks max
    __shared__ unsigned short Bs[N][40];
    const int tid = threadIdx.x;
    const int w = tid >> 6, lane = tid & 63;
    const int g = lane >> 4, r16 = lane & 15;
    const int bm = blockIdx.x;

    const int sArow = tid >> 2;
    const int sAkq = (tid & 3) * 8;
    const int garow = bm * 64 + sArow;

    f32x4 acc[16] = {};

    for (int k0 = 0; k0 < K; k0 += 32) {
        uint4 av = make_uint4(0, 0, 0, 0);
        if (garow < M) av = *(const uint4*)&A[(size_t)garow * K + k0 + sAkq];
        uint4 bv0 = *(const uint4*)&Bt[(size_t)tid * K + k0 + 0];
        uint4 bv1 = *(const uint4*)&Bt[(size_t)tid * K + k0 + 8];
        uint4 bv2 = *(const uint4*)&Bt[(size_t)tid * K + k0 + 16];
        uint4 bv3 = *(const uint4*)&Bt[(size_t)tid * K + k0 + 24];
        __syncthreads();   // protect previous iteration's LDS reads
        *(uint4*)&As[sArow][sAkq] = av;
        *(uint4*)&Bs[tid][0] = bv0;
        *(uint4*)&Bs[tid][8] = bv1;
        *(uint4*)&Bs[tid][16] = bv2;
        *(uint4*)&Bs[tid][24] = bv3;
        __syncthreads();

        s16x8 af = *(const s16x8*)&As[w * 16 + r16][g * 8];
#pragma unroll
        for (int cg = 0; cg < 16; ++cg) {
            s16x8 bf = *(const s16x8*)&Bs[cg * 16 + r16][g * 8];
            acc[cg] = __builtin_amdgcn_mfma_f32_16x16x32_bf16(af, bf, acc[cg], 0, 0, 0);
        }
    }

    // C/D layout: col = cg*16 + (lane&15); row (within wave) = (lane>>4)*4 + reg
    if constexpr (!FUSE3) {
#pragma unroll
        for (int cg = 0; cg < 16; ++cg) {
            int col = cg * 16 + r16;
            float bs = bias[col];
#pragma unroll
            for (int r = 0; r < 4; ++r) {
                int row = bm * 64 + w * 16 + g * 4 + r;
                if (row < M) {
                    float v = fmaxf(acc[cg][r] + bs, 0.f);
                    Cb[(size_t)row * N + col] = f2b(v);
                }
            }
        }
    } else {
        // stage W3 [256][10] fp32 into LDS (reuse Bs region)
        float* W3s = (float*)&Bs[0][0];
        __syncthreads();
        for (int i = tid; i < N * F_OUT; i += 256) W3s[i] = W3[i];
        __syncthreads();

        float bcol[16];
#pragma unroll
        for (int cg = 0; cg < 16; ++cg) bcol[cg] = bias[cg * 16 + r16];

#pragma unroll
        for (int r = 0; r < 4; ++r) {
            float pj[F_OUT] = {};
#pragma unroll
            for (int cg = 0; cg < 16; ++cg) {
                float v = fmaxf(acc[cg][r] + bcol[cg], 0.f);
                const float* w3r = &W3s[(cg * 16 + r16) * F_OUT];
#pragma unroll
                for (int j = 0; j < F_OUT; ++j) pj[j] += v * w3r[j];
            }
#pragma unroll
            for (int j = 0; j < F_OUT; ++j) {
                pj[j] += __shfl_xor(pj[j], 1);
                pj[j] += __shfl_xor(pj[j], 2);
                pj[j] += __shfl_xor(pj[j], 4);
                pj[j] += __shfl_xor(pj[j], 8);
            }
            if (r16 == 0) {
                int row = bm * 64 + w * 16 + g * 4 + r;
                if (row < M) {
#pragma unroll
                    for (int j = 0; j < F_OUT; ++j) hw3[(size_t)row * F_OUT + j] = pj[j];
                }
            }
        }
    }
}

// ---------------- final: 10-dim aggregation + bias + log_softmax ----------------

__global__ void final_kernel(const float* __restrict__ hw3, const int* __restrict__ rowstart,
                             const int2* __restrict__ pack, const float* __restrict__ dinv,
                             const float* __restrict__ b3, float* __restrict__ out, int n) {
    int v = blockIdx.x * blockDim.x + threadIdx.x;
    if (v >= n) return;
    float acc[F_OUT];
    float d = dinv[v];
    float sw = d * d;
#pragma unroll
    for (int j = 0; j < F_OUT; ++j) acc[j] = sw * hw3[(size_t)v * F_OUT + j];
    int e0 = rowstart[v], e1 = rowstart[v + 1];
    for (int e = e0; e < e1; ++e) {
        int2 p = pack[e];
        float w = __int_as_float(p.y);
#pragma unroll
        for (int j = 0; j < F_OUT; ++j) acc[j] += w * hw3[(size_t)p.x * F_OUT + j];
    }
#pragma unroll
    for (int j = 0; j < F_OUT; ++j) acc[j] += b3[j];
    float m = acc[0];
#pragma unroll
    for (int j = 1; j < F_OUT; ++j) m = fmaxf(m, acc[j]);
    float sum = 0.f;
#pragma unroll
    for (int j = 0; j < F_OUT; ++j) sum += expf(acc[j] - m);
    float lse = m + logf(sum);
#pragma unroll
    for (int j = 0; j < F_OUT; ++j) out[(size_t)v * F_OUT + j] = acc[j] - lse;
}

// ---------------- launch ----------------

extern "C" void kernel_launch(void* const* d_in, const int* in_sizes, int n_in,
                              void* d_out, int out_size, void* d_ws, size_t ws_size,
                              hipStream_t stream) {
    const float* x  = (const float*)d_in[0];
    const int*   ei = (const int*)d_in[1];
    const float* W1 = (const float*)d_in[2];
    const float* b1 = (const float*)d_in[3];
    const float* W2 = (const float*)d_in[4];
    const float* b2 = (const float*)d_in[5];
    const float* W3 = (const float*)d_in[6];
    const float* b3 = (const float*)d_in[7];
    float* out = (float*)d_out;

    int n = in_sizes[0] / F_IN;
    int e = in_sizes[1] / 2;
    const int* srcp = ei;
    const int* dstp = ei + e;

    size_t off = 0;
    auto alloc = [&](size_t bytes) -> char* {
        char* p = (char*)d_ws + off;
        off += (bytes + 255) & ~(size_t)255;
        return p;
    };
    size_t cntpad = ((size_t)n * 4 + 255) & ~(size_t)255;
    int*   cnt      = (int*)alloc((size_t)n * 4);
    int*   cursor   = (int*)alloc((size_t)n * 4);   // adjacent to cnt: single memset
    int*   rowstart = (int*)alloc((size_t)(n + 1) * 4);
    int*   partial  = (int*)alloc(1024 * 4);
    int2*  pack     = (int2*)alloc((size_t)e * 8);
    float* dinv     = (float*)alloc((size_t)n * 4);
    unsigned short* xb   = (unsigned short*)alloc((size_t)n * F_IN * 2);   // x bf16
    unsigned short* aggb = (unsigned short*)alloc((size_t)n * F_HID * 2);  // agg out bf16
    unsigned short* h1b  = (unsigned short*)alloc((size_t)n * F_HID * 2);  // h1 bf16
    unsigned short* W1t  = (unsigned short*)alloc((size_t)F_IN * F_HID * 2);
    unsigned short* W2t  = (unsigned short*)alloc((size_t)F_HID * F_HID * 2);
    float* hw3 = (float*)alloc((size_t)n * F_OUT * 4);

    const int TB = 256;
    // one memset covers cnt + cursor (adjacent)
    hipMemsetAsync(cnt, 0, cntpad + (size_t)n * 4, stream);

    // prep: count + cast x + castT W1 + castT W2
    int xq = (int)((size_t)n * F_IN / 4);
    int prepmax = e > xq ? e : xq;
    dim3 gp((prepmax + TB - 1) / TB, 4);
    prep_kernel<<<gp, TB, 0, stream>>>(dstp, cnt, e, x, xb, xq, W1, W1t, W2, W2t);

    int nb = (n + TB - 1) / TB;
    scan1_kernel<<<nb, TB, 0, stream>>>(cnt, rowstart, partial, dinv, n);
    scan2_kernel<<<1, TB, 0, stream>>>(partial, nb);
    scan3_kernel<<<nb, TB, 0, stream>>>(rowstart, partial, n, e);
    fill_kernel<<<(e + TB - 1) / TB, TB, 0, stream>>>(srcp, dstp, rowstart, cursor, dinv,
                                                      pack, e);

    int nwave = (n + 3) / 4;
    int gblocks = (n + 63) / 64;

    // Layer 1: aggregate x_bf16 (128) -> aggb, MFMA GEMM+bias+relu -> h1 (bf16)
    agg_kernel<F_IN><<<nwave, 256, 0, stream>>>(xb, rowstart, pack, dinv, aggb, n);
    gemm_kernel<F_IN, false><<<gblocks, 256, 0, stream>>>(aggb, W1t, b1, h1b, nullptr, nullptr, n);

    // Layer 2: aggregate h1_bf16 (256) -> aggb, fused GEMM2+relu+GEMM3 -> hw3 (fp32)
    agg_kernel<F_HID><<<nwave, 256, 0, stream>>>(h1b, rowstart, pack, dinv, aggb, n);
    gemm_kernel<F_HID, true><<<gblocks, 256, 0, stream>>>(aggb, W2t, b2, nullptr, W3, hw3, n);

    // final: 10-dim aggregation + bias + log_softmax
    final_kernel<<<(n + 255) / 256, 256, 0, stream>>>(hw3, rowstart, pack, dinv, b3, out, n);
}